// Round 1
// baseline (723.537 us; speedup 1.0000x reference)
//
#include <hip/hip_runtime.h>

// TemporalGNN: 2x TransformerConv(H=2, C=64) + edge encoder + fc head.
// Key simplification: edge_attr is [E,1], so eh_l = ea[e]*u_l + c_l where
// u_l = We_enc_row @ We_l  (128 floats), c_l = be_enc @ We_l (128 floats).

#define HC 128   // H*C
#define NPB 16   // nodes per block in the linear kernel

__device__ __forceinline__ unsigned enc_f(float f) {
    unsigned u = __float_as_uint(f);
    return (u & 0x80000000u) ? ~u : (u | 0x80000000u);
}
__device__ __forceinline__ float dec_f(unsigned u) {
    u = (u & 0x80000000u) ? (u & 0x7fffffffu) : ~u;
    return __uint_as_float(u);
}

// Precompute u1,c1,u2,c2 (4 x 128 floats) from the rank-1 edge encoder.
__global__ void k_uc(const float* __restrict__ We_enc, const float* __restrict__ be_enc,
                     const float* __restrict__ We1, const float* __restrict__ We2,
                     float* __restrict__ uc) {
    int c = threadIdx.x;  // 0..127
    float u1 = 0.f, c1 = 0.f, u2 = 0.f, c2 = 0.f;
    for (int j = 0; j < 64; ++j) {
        float we = We_enc[j], be = be_enc[j];
        float w1 = We1[j * HC + c], w2 = We2[j * HC + c];
        u1 += we * w1; c1 += be * w1;
        u2 += we * w2; c2 += be * w2;
    }
    uc[c] = u1; uc[HC + c] = c1; uc[2 * HC + c] = u2; uc[3 * HC + c] = c2;
}

// Fused node linears: q = X@Wq+bq, k = X@Wk+bk, v = X@Wv+bv, o = X@Ws+bs.
// 16 nodes/block staged in LDS; weights read once per block (register-blocked).
// Safe for X == o aliasing: each block reads its own 16 rows into LDS before
// writing, and blocks own disjoint node ranges.
template <int K>
__global__ __launch_bounds__(256) void k_lin(
    const float* __restrict__ X, int n,
    const float* __restrict__ Wq, const float* __restrict__ bq,
    const float* __restrict__ Wk, const float* __restrict__ bk,
    const float* __restrict__ Wv, const float* __restrict__ bv,
    const float* __restrict__ Ws, const float* __restrict__ bs,
    float* __restrict__ q, float* __restrict__ k,
    float* __restrict__ v, float* __restrict__ o) {
    __shared__ float xs[NPB][K];
    const int base = blockIdx.x * NPB;
    const int tid = threadIdx.x;
    for (int i = tid; i < NPB * K; i += 256) {
        int ni = base + i / K;
        xs[i / K][i % K] = (ni < n) ? X[(size_t)ni * K + (i % K)] : 0.f;
    }
    __syncthreads();
    const int c = tid & 127;
    const int m = tid >> 7;  // 0 -> (q,k), 1 -> (v,o)
    const float* WA = m ? Wv : Wq;
    const float* WB = m ? Ws : Wk;
    float accA[NPB], accB[NPB];
#pragma unroll
    for (int i = 0; i < NPB; ++i) { accA[i] = 0.f; accB[i] = 0.f; }
    for (int j = 0; j < K; ++j) {
        float w0 = WA[j * HC + c];
        float w1 = WB[j * HC + c];
#pragma unroll
        for (int i = 0; i < NPB; ++i) {
            float xv = xs[i][j];
            accA[i] += xv * w0;
            accB[i] += xv * w1;
        }
    }
    const float bA = m ? bv[c] : bq[c];
    const float bB = m ? bs[c] : bk[c];
    float* oA = m ? v : q;
    float* oB = m ? o : k;
    for (int i = 0; i < NPB; ++i) {
        int ni = base + i;
        if (ni < n) {
            oA[(size_t)ni * HC + c] = accA[i] + bA;
            oB[(size_t)ni * HC + c] = accB[i] + bB;
        }
    }
}

// One 64-lane wave per edge: alpha[e,h] = dot(q[dst,h,:], k[src,h,:]+eh)/8,
// then atomicMax into encoded per-(dst,head) max.
__global__ __launch_bounds__(256) void k_alpha(
    const float* __restrict__ q, const float* __restrict__ k,
    const int* __restrict__ ei, const float* __restrict__ ea,
    const float* __restrict__ u, const float* __restrict__ cv,
    int E, float* __restrict__ alpha, unsigned* __restrict__ mmax) {
    int w = (int)((blockIdx.x * (size_t)blockDim.x + threadIdx.x) >> 6);
    int lane = threadIdx.x & 63;
    if (w >= E) return;
    int src = ei[w];
    int dst = ei[E + w];
    float eav = ea[w];
    int i0 = lane, i1 = 64 + lane;
    float eh0 = eav * u[i0] + cv[i0];
    float eh1 = eav * u[i1] + cv[i1];
    const float* qr = q + (size_t)dst * HC;
    const float* kr = k + (size_t)src * HC;
    float v0 = qr[i0] * (kr[i0] + eh0);
    float v1 = qr[i1] * (kr[i1] + eh1);
#pragma unroll
    for (int off = 1; off < 64; off <<= 1) {
        v0 += __shfl_xor(v0, off);
        v1 += __shfl_xor(v1, off);
    }
    if (lane == 0) {
        float a0 = v0 * 0.125f;
        float a1 = v1 * 0.125f;
        alpha[(size_t)w * 2] = a0;
        alpha[(size_t)w * 2 + 1] = a1;
        atomicMax(&mmax[dst * 2], enc_f(a0));
        atomicMax(&mmax[dst * 2 + 1], enc_f(a1));
    }
}

// ex = exp(alpha - m[dst]); alpha <- ex; s[dst,h] += ex.
__global__ __launch_bounds__(256) void k_exp(
    float* __restrict__ alpha, const int* __restrict__ ei,
    const unsigned* __restrict__ mmax, float* __restrict__ s, int E) {
    int t = blockIdx.x * blockDim.x + threadIdx.x;
    if (t >= E * 2) return;
    int e = t >> 1, h = t & 1;
    int dst = ei[E + e];
    float m = dec_f(mmax[dst * 2 + h]);
    float ex = __expf(alpha[t] - m);
    alpha[t] = ex;
    atomicAdd(&s[dst * 2 + h], ex);
}

// One wave per edge: out[dst] += (v[src]+eh) * ex/(s[dst]+1e-16).
__global__ __launch_bounds__(256) void k_msg(
    const float* __restrict__ v, const int* __restrict__ ei, const float* __restrict__ ea,
    const float* __restrict__ u, const float* __restrict__ cv,
    const float* __restrict__ alpha, const float* __restrict__ s,
    int E, float* __restrict__ out) {
    int w = (int)((blockIdx.x * (size_t)blockDim.x + threadIdx.x) >> 6);
    int lane = threadIdx.x & 63;
    if (w >= E) return;
    int src = ei[w];
    int dst = ei[E + w];
    float eav = ea[w];
    float c0 = alpha[(size_t)w * 2] / (s[dst * 2] + 1e-16f);
    float c1 = alpha[(size_t)w * 2 + 1] / (s[dst * 2 + 1] + 1e-16f);
    int i0 = lane, i1 = 64 + lane;
    float eh0 = eav * u[i0] + cv[i0];
    float eh1 = eav * u[i1] + cv[i1];
    const float* vr = v + (size_t)src * HC;
    atomicAdd(&out[(size_t)dst * HC + i0], (vr[i0] + eh0) * c0);
    atomicAdd(&out[(size_t)dst * HC + i1], (vr[i1] + eh1) * c1);
}

__global__ __launch_bounds__(256) void k_relu(float* __restrict__ b, int n) {
    int t = blockIdx.x * blockDim.x + threadIdx.x;
    if (t < n) b[t] = fmaxf(b[t], 0.f);
}

// out[n] = relu(h[n,:]) @ Wfc + bfc, one wave per node.
__global__ __launch_bounds__(256) void k_fc(
    const float* __restrict__ h, const float* __restrict__ Wfc,
    const float* __restrict__ bfc, float* __restrict__ out, int n) {
    int w = (int)((blockIdx.x * (size_t)blockDim.x + threadIdx.x) >> 6);
    int lane = threadIdx.x & 63;
    if (w >= n) return;
    const float* hr = h + (size_t)w * HC;
    float v = fmaxf(hr[lane], 0.f) * Wfc[lane] + fmaxf(hr[64 + lane], 0.f) * Wfc[64 + lane];
#pragma unroll
    for (int off = 1; off < 64; off <<= 1) v += __shfl_xor(v, off);
    if (lane == 0) out[w] = v + bfc[0];
}

extern "C" void kernel_launch(void* const* d_in, const int* in_sizes, int n_in,
                              void* d_out, int out_size, void* d_ws, size_t ws_size,
                              hipStream_t stream) {
    const float* x      = (const float*)d_in[0];
    const int*   ei     = (const int*)d_in[1];
    const float* ea     = (const float*)d_in[2];
    const float* We_enc = (const float*)d_in[3];
    const float* be_enc = (const float*)d_in[4];
    const float* Wq1 = (const float*)d_in[5],  *bq1 = (const float*)d_in[6];
    const float* Wk1 = (const float*)d_in[7],  *bk1 = (const float*)d_in[8];
    const float* Wv1 = (const float*)d_in[9],  *bv1 = (const float*)d_in[10];
    const float* We1 = (const float*)d_in[11];
    const float* Ws1 = (const float*)d_in[12], *bs1 = (const float*)d_in[13];
    const float* Wq2 = (const float*)d_in[14], *bq2 = (const float*)d_in[15];
    const float* Wk2 = (const float*)d_in[16], *bk2 = (const float*)d_in[17];
    const float* Wv2 = (const float*)d_in[18], *bv2 = (const float*)d_in[19];
    const float* We2 = (const float*)d_in[20];
    const float* Ws2 = (const float*)d_in[21], *bs2 = (const float*)d_in[22];
    const float* Wfc = (const float*)d_in[23], *bfc = (const float*)d_in[24];

    const int n = in_sizes[0] / 6;   // 50000
    const int E = in_sizes[2];       // 409600

    float* ws = (float*)d_ws;
    size_t off = 0;
    float* qb = ws + off; off += (size_t)n * HC;
    float* kb = ws + off; off += (size_t)n * HC;
    float* vb = ws + off; off += (size_t)n * HC;
    float* Bb = ws + off; off += (size_t)n * HC;   // accum / h buffer (reused in-place)
    float* alpha = ws + off; off += (size_t)E * 2;
    unsigned* mmax = (unsigned*)(ws + off); off += (size_t)n * 2;
    float* sb = ws + off; off += (size_t)n * 2;
    float* uc = ws + off; off += 512;

    hipLaunchKernelGGL(k_uc, dim3(1), dim3(128), 0, stream, We_enc, be_enc, We1, We2, uc);

    const int eblocks = (int)(((size_t)E * 64 + 255) / 256);
    const int linblocks = (n + NPB - 1) / NPB;

    // ---- layer 1 ----
    hipMemsetAsync(mmax, 0, (size_t)n * 2 * sizeof(unsigned), stream);
    hipMemsetAsync(sb, 0, (size_t)n * 2 * sizeof(float), stream);
    hipLaunchKernelGGL(k_lin<6>, dim3(linblocks), dim3(256), 0, stream,
                       x, n, Wq1, bq1, Wk1, bk1, Wv1, bv1, Ws1, bs1, qb, kb, vb, Bb);
    hipLaunchKernelGGL(k_alpha, dim3(eblocks), dim3(256), 0, stream,
                       qb, kb, ei, ea, uc, uc + HC, E, alpha, mmax);
    hipLaunchKernelGGL(k_exp, dim3((E * 2 + 255) / 256), dim3(256), 0, stream,
                       alpha, ei, mmax, sb, E);
    hipLaunchKernelGGL(k_msg, dim3(eblocks), dim3(256), 0, stream,
                       vb, ei, ea, uc, uc + HC, alpha, sb, E, Bb);
    hipLaunchKernelGGL(k_relu, dim3((int)(((size_t)n * HC + 255) / 256)), dim3(256), 0, stream,
                       Bb, n * HC);

    // ---- layer 2 (lin reads Bb as input and overwrites it with skip-init) ----
    hipMemsetAsync(mmax, 0, (size_t)n * 2 * sizeof(unsigned), stream);
    hipMemsetAsync(sb, 0, (size_t)n * 2 * sizeof(float), stream);
    hipLaunchKernelGGL(k_lin<HC>, dim3(linblocks), dim3(256), 0, stream,
                       Bb, n, Wq2, bq2, Wk2, bk2, Wv2, bv2, Ws2, bs2, qb, kb, vb, Bb);
    hipLaunchKernelGGL(k_alpha, dim3(eblocks), dim3(256), 0, stream,
                       qb, kb, ei, ea, uc + 2 * HC, uc + 3 * HC, E, alpha, mmax);
    hipLaunchKernelGGL(k_exp, dim3((E * 2 + 255) / 256), dim3(256), 0, stream,
                       alpha, ei, mmax, sb, E);
    hipLaunchKernelGGL(k_msg, dim3(eblocks), dim3(256), 0, stream,
                       vb, ei, ea, uc + 2 * HC, uc + 3 * HC, alpha, sb, E, Bb);

    // ---- fc head (relu fused) ----
    hipLaunchKernelGGL(k_fc, dim3((int)(((size_t)n * 64 + 255) / 256)), dim3(256), 0, stream,
                       Bb, Wfc, bfc, (float*)d_out, n);
}

// Round 2
// 476.671 us; speedup vs baseline: 1.5179x; 1.5179x over previous
//
#include <hip/hip_runtime.h>

// TemporalGNN: 2x TransformerConv(H=2, C=64) + edge encoder + fc head.
// Edge encoder is rank-1 (edge_attr is [E,1]): eh_l = ea[e]*u_l + c_l with
// u_l = We_enc_row @ We_l, c_l = be_enc @ We_l (128 floats each).
// Edge phase: stable counting-sort edges by dst once per call, then one wave
// per dst node does online-softmax attention with a single output write
// (no atomics on the output).

#define HC 128   // H*C

// ---------- rank-1 edge-encoder precompute ----------
__global__ void k_uc(const float* __restrict__ We_enc, const float* __restrict__ be_enc,
                     const float* __restrict__ We1, const float* __restrict__ We2,
                     float* __restrict__ uc) {
    int c = threadIdx.x;  // 0..127
    float u1 = 0.f, c1 = 0.f, u2 = 0.f, c2 = 0.f;
    for (int j = 0; j < 64; ++j) {
        float we = We_enc[j], be = be_enc[j];
        float w1 = We1[j * HC + c], w2 = We2[j * HC + c];
        u1 += we * w1; c1 += be * w1;
        u2 += we * w2; c2 += be * w2;
    }
    uc[c] = u1; uc[HC + c] = c1; uc[2 * HC + c] = u2; uc[3 * HC + c] = c2;
}

// ---------- CSR build (stable counting sort by dst) ----------
__global__ __launch_bounds__(256) void k_hist(const int* __restrict__ ei, int* __restrict__ deg, int E) {
    int t = blockIdx.x * blockDim.x + threadIdx.x;
    if (t < E) atomicAdd(&deg[ei[E + t]], 1);
}

// Single-workgroup exclusive scan over n degrees -> rowptr[n+1].
__global__ __launch_bounds__(1024) void k_scan(const int* __restrict__ deg, int* __restrict__ rowptr, int n) {
    __shared__ int part[1024];
    const int tid = threadIdx.x;
    const int per = (n + 1023) / 1024;
    int b = tid * per;
    int e = min(b + per, n);
    int s = 0;
    for (int i = b; i < e; ++i) s += deg[i];
    part[tid] = s;
    __syncthreads();
    for (int off = 1; off < 1024; off <<= 1) {
        int v = (tid >= off) ? part[tid - off] : 0;
        __syncthreads();
        part[tid] += v;
        __syncthreads();
    }
    int run = (tid == 0) ? 0 : part[tid - 1];
    for (int i = b; i < e; ++i) { rowptr[i] = run; run += deg[i]; }
    if (tid == 1023) rowptr[n] = run;
}

__global__ __launch_bounds__(256) void k_scatter(const int* __restrict__ ei, const int* __restrict__ rowptr,
                                                 int* __restrict__ cursor, int* __restrict__ eid, int E) {
    int t = blockIdx.x * blockDim.x + threadIdx.x;
    if (t >= E) return;
    int dst = ei[E + t];
    int pos = rowptr[dst] + atomicAdd(&cursor[dst], 1);
    eid[pos] = t;
}

// Per-bucket insertion sort by edge id -> deterministic (stable) order.
__global__ __launch_bounds__(256) void k_bsort(const int* __restrict__ rowptr, int* __restrict__ eid, int n) {
    int t = blockIdx.x * blockDim.x + threadIdx.x;
    if (t >= n) return;
    int b = rowptr[t], e = rowptr[t + 1];
    for (int i = b + 1; i < e; ++i) {
        int key = eid[i];
        int j = i - 1;
        while (j >= b && eid[j] > key) { eid[j + 1] = eid[j]; --j; }
        eid[j + 1] = key;
    }
}

__global__ __launch_bounds__(256) void k_gather(const int* __restrict__ eid, const int* __restrict__ ei,
                                                const float* __restrict__ ea,
                                                int* __restrict__ srcs, float* __restrict__ eas, int E) {
    int t = blockIdx.x * blockDim.x + threadIdx.x;
    if (t >= E) return;
    int id = eid[t];
    srcs[t] = ei[id];
    eas[t] = ea[id];
}

// ---------- fused node linears ----------
// q = X@Wq+bq, k = X@Wk+bk, v = X@Wv+bv, o = X@Ws+bs. NPB nodes/block in LDS.
// Safe for X == o aliasing (block reads its own rows before writing).
template <int K, int NPB>
__global__ __launch_bounds__(256) void k_lin(
    const float* __restrict__ X, int n,
    const float* __restrict__ Wq, const float* __restrict__ bq,
    const float* __restrict__ Wk, const float* __restrict__ bk,
    const float* __restrict__ Wv, const float* __restrict__ bv,
    const float* __restrict__ Ws, const float* __restrict__ bs,
    float* __restrict__ q, float* __restrict__ k,
    float* __restrict__ v, float* __restrict__ o) {
    __shared__ __align__(16) float xs[NPB][K];
    const int base = blockIdx.x * NPB;
    const int tid = threadIdx.x;
    for (int i = tid; i < NPB * K; i += 256) {
        int ni = base + i / K;
        xs[i / K][i % K] = (ni < n) ? X[(size_t)ni * K + (i % K)] : 0.f;
    }
    __syncthreads();
    const int c = tid & 127;
    const int m = tid >> 7;  // 0 -> (q,k), 1 -> (v,o)
    const float* WA = m ? Wv : Wq;
    const float* WB = m ? Ws : Wk;
    float accA[NPB], accB[NPB];
#pragma unroll
    for (int i = 0; i < NPB; ++i) { accA[i] = 0.f; accB[i] = 0.f; }
    if constexpr (K % 4 == 0) {
        for (int j4 = 0; j4 < K / 4; ++j4) {
            float wa0 = WA[(j4 * 4 + 0) * HC + c], wa1 = WA[(j4 * 4 + 1) * HC + c];
            float wa2 = WA[(j4 * 4 + 2) * HC + c], wa3 = WA[(j4 * 4 + 3) * HC + c];
            float wb0 = WB[(j4 * 4 + 0) * HC + c], wb1 = WB[(j4 * 4 + 1) * HC + c];
            float wb2 = WB[(j4 * 4 + 2) * HC + c], wb3 = WB[(j4 * 4 + 3) * HC + c];
#pragma unroll
            for (int i = 0; i < NPB; ++i) {
                float4 xv = ((const float4*)xs[i])[j4];
                accA[i] += xv.x * wa0 + xv.y * wa1 + xv.z * wa2 + xv.w * wa3;
                accB[i] += xv.x * wb0 + xv.y * wb1 + xv.z * wb2 + xv.w * wb3;
            }
        }
    } else {
        for (int j = 0; j < K; ++j) {
            float w0 = WA[j * HC + c];
            float w1 = WB[j * HC + c];
#pragma unroll
            for (int i = 0; i < NPB; ++i) {
                float xv = xs[i][j];
                accA[i] += xv * w0;
                accB[i] += xv * w1;
            }
        }
    }
    const float bA = m ? bv[c] : bq[c];
    const float bB = m ? bs[c] : bk[c];
    float* oA = m ? v : q;
    float* oB = m ? o : k;
#pragma unroll
    for (int i = 0; i < NPB; ++i) {
        int ni = base + i;
        if (ni < n) {
            oA[(size_t)ni * HC + c] = accA[i] + bA;
            oB[(size_t)ni * HC + c] = accB[i] + bB;
        }
    }
}

// ---------- fused online-softmax attention, one wave per dst node ----------
// Lane l holds channels {2l, 2l+1}; lanes 0..31 = head0, 32..63 = head1.
// io holds the skip term on entry; overwritten with the layer output.
template <int RELU>
__global__ __launch_bounds__(256) void k_attn(
    const float* __restrict__ q, const float* __restrict__ k, const float* __restrict__ v,
    const int* __restrict__ rowptr, const int* __restrict__ srcs, const float* __restrict__ eas,
    const float* __restrict__ ucu, const float* __restrict__ ucc,
    float* __restrict__ io, int n) {
    int wid = (int)((blockIdx.x * (size_t)blockDim.x + threadIdx.x) >> 6);
    int lane = threadIdx.x & 63;
    if (wid >= n) return;
    const float2* q2 = (const float2*)q;
    const float2* k2 = (const float2*)k;
    const float2* v2 = (const float2*)v;
    float2 qr = q2[(size_t)wid * 64 + lane];
    float2 uu = ((const float2*)ucu)[lane];
    float2 cc = ((const float2*)ucc)[lane];
    int b = rowptr[wid], e = rowptr[wid + 1];
    float m = -INFINITY, s = 0.f;
    float ax = 0.f, ay = 0.f;
    for (int p = b; p < e; ++p) {
        int src = srcs[p];
        float eav = eas[p];
        float2 kr = k2[(size_t)src * 64 + lane];
        float2 vr = v2[(size_t)src * 64 + lane];
        float eh0 = eav * uu.x + cc.x;
        float eh1 = eav * uu.y + cc.y;
        float d = qr.x * (kr.x + eh0) + qr.y * (kr.y + eh1);
        d += __shfl_xor(d, 1); d += __shfl_xor(d, 2); d += __shfl_xor(d, 4);
        d += __shfl_xor(d, 8); d += __shfl_xor(d, 16);   // per-head (32-lane) sum
        float a = d * 0.125f;                            // / sqrt(64)
        float nm = fmaxf(m, a);
        float sc = __expf(m - nm);
        float pw = __expf(a - nm);
        s = s * sc + pw;
        ax = ax * sc + pw * (vr.x + eh0);
        ay = ay * sc + pw * (vr.y + eh1);
        m = nm;
    }
    float inv = 1.f / (s + 1e-16f);
    float2 skip = ((const float2*)io)[(size_t)wid * 64 + lane];
    float o0 = ax * inv + skip.x;
    float o1 = ay * inv + skip.y;
    if (RELU) { o0 = fmaxf(o0, 0.f); o1 = fmaxf(o1, 0.f); }
    ((float2*)io)[(size_t)wid * 64 + lane] = make_float2(o0, o1);
}

// ---------- fc head (relu fused), one wave per node ----------
__global__ __launch_bounds__(256) void k_fc(
    const float* __restrict__ h, const float* __restrict__ Wfc,
    const float* __restrict__ bfc, float* __restrict__ out, int n) {
    int w = (int)((blockIdx.x * (size_t)blockDim.x + threadIdx.x) >> 6);
    int lane = threadIdx.x & 63;
    if (w >= n) return;
    const float2* h2 = (const float2*)h;
    const float2* w2 = (const float2*)Wfc;
    float2 hv = h2[(size_t)w * 64 + lane];
    float2 wv = w2[lane];
    float vsum = fmaxf(hv.x, 0.f) * wv.x + fmaxf(hv.y, 0.f) * wv.y;
#pragma unroll
    for (int off = 1; off < 64; off <<= 1) vsum += __shfl_xor(vsum, off);
    if (lane == 0) out[w] = vsum + bfc[0];
}

extern "C" void kernel_launch(void* const* d_in, const int* in_sizes, int n_in,
                              void* d_out, int out_size, void* d_ws, size_t ws_size,
                              hipStream_t stream) {
    const float* x      = (const float*)d_in[0];
    const int*   ei     = (const int*)d_in[1];
    const float* ea     = (const float*)d_in[2];
    const float* We_enc = (const float*)d_in[3];
    const float* be_enc = (const float*)d_in[4];
    const float* Wq1 = (const float*)d_in[5],  *bq1 = (const float*)d_in[6];
    const float* Wk1 = (const float*)d_in[7],  *bk1 = (const float*)d_in[8];
    const float* Wv1 = (const float*)d_in[9],  *bv1 = (const float*)d_in[10];
    const float* We1 = (const float*)d_in[11];
    const float* Ws1 = (const float*)d_in[12], *bs1 = (const float*)d_in[13];
    const float* Wq2 = (const float*)d_in[14], *bq2 = (const float*)d_in[15];
    const float* Wk2 = (const float*)d_in[16], *bk2 = (const float*)d_in[17];
    const float* Wv2 = (const float*)d_in[18], *bv2 = (const float*)d_in[19];
    const float* We2 = (const float*)d_in[20];
    const float* Ws2 = (const float*)d_in[21], *bs2 = (const float*)d_in[22];
    const float* Wfc = (const float*)d_in[23], *bfc = (const float*)d_in[24];

    const int n = in_sizes[0] / 6;   // 50000
    const int E = in_sizes[2];       // 409600

    float* ws = (float*)d_ws;
    size_t off = 0;
    float* qb = ws + off; off += (size_t)n * HC;
    float* kb = ws + off; off += (size_t)n * HC;
    float* vb = ws + off; off += (size_t)n * HC;
    float* Bb = ws + off; off += (size_t)n * HC;   // skip-init / h buffer (in-place)
    int* rowptr = (int*)(ws + off); off += (size_t)(n + 1);
    int* deg    = (int*)(ws + off); off += (size_t)n;   // also scatter cursor
    int* eid    = (int*)(ws + off); off += (size_t)E;
    int* srcs   = (int*)(ws + off); off += (size_t)E;
    float* eas  = ws + off; off += (size_t)E;
    float* uc   = ws + off; off += 512;

    const int eb = (E + 255) / 256;
    const int nb = (n + 255) / 256;
    const int wb = (int)(((size_t)n * 64 + 255) / 256);

    hipLaunchKernelGGL(k_uc, dim3(1), dim3(128), 0, stream, We_enc, be_enc, We1, We2, uc);

    // ---- CSR build (shared by both layers) ----
    hipMemsetAsync(deg, 0, (size_t)n * sizeof(int), stream);
    hipLaunchKernelGGL(k_hist, dim3(eb), dim3(256), 0, stream, ei, deg, E);
    hipLaunchKernelGGL(k_scan, dim3(1), dim3(1024), 0, stream, deg, rowptr, n);
    hipMemsetAsync(deg, 0, (size_t)n * sizeof(int), stream);  // reuse as cursor
    hipLaunchKernelGGL(k_scatter, dim3(eb), dim3(256), 0, stream, ei, rowptr, deg, eid, E);
    hipLaunchKernelGGL(k_bsort, dim3(nb), dim3(256), 0, stream, rowptr, eid, n);
    hipLaunchKernelGGL(k_gather, dim3(eb), dim3(256), 0, stream, eid, ei, ea, srcs, eas, E);

    // ---- layer 1 ----
    hipLaunchKernelGGL((k_lin<6, 16>), dim3((n + 15) / 16), dim3(256), 0, stream,
                       x, n, Wq1, bq1, Wk1, bk1, Wv1, bv1, Ws1, bs1, qb, kb, vb, Bb);
    hipLaunchKernelGGL((k_attn<1>), dim3(wb), dim3(256), 0, stream,
                       qb, kb, vb, rowptr, srcs, eas, uc, uc + HC, Bb, n);

    // ---- layer 2 ----
    hipLaunchKernelGGL((k_lin<HC, 32>), dim3((n + 31) / 32), dim3(256), 0, stream,
                       Bb, n, Wq2, bq2, Wk2, bk2, Wv2, bv2, Ws2, bs2, qb, kb, vb, Bb);
    hipLaunchKernelGGL((k_attn<0>), dim3(wb), dim3(256), 0, stream,
                       qb, kb, vb, rowptr, srcs, eas, uc + 2 * HC, uc + 3 * HC, Bb, n);

    // ---- fc head ----
    hipLaunchKernelGGL(k_fc, dim3(wb), dim3(256), 0, stream, Bb, Wfc, bfc, (float*)d_out, n);
}